// Round 8
// baseline (136.703 us; speedup 1.0000x reference)
//
#include <hip/hip_runtime.h>

#define KN 1000000
#define NCOLS 70400
#define NPAIRS (KN / 32)          // 2 elem-tiles (32 elems) per wave-iteration
#define NBLK 1024
#define NTHR 256
#define NREP 8                    // one replica per XCD (XCC_ID 0..7)

typedef _Float16 f16x4 __attribute__((ext_vector_type(4)));
typedef float    f32x4 __attribute__((ext_vector_type(4)));

// 16x16x16 f16 MFMA: A[m][k] m=lane&15, k=quad*4+j; B[k][n] n=lane&15,
// k=quad*4+j; D[m][n] n=lane&15, m=quad*4+r.  A, B, D share per-lane
// structure -> relu(D) of layer L is directly the B-operand of layer L+1.
#define MFMA16(a, b, c) __builtin_amdgcn_mfma_f32_16x16x16f16((a), (b), (c), 0, 0, 0)

__device__ __forceinline__ unsigned encodeF(float f) {
    unsigned b = __float_as_uint(f);
    return (b & 0x80000000u) ? ~b : (b | 0x80000000u);
}
__device__ __forceinline__ float decodeF(unsigned e) {
    unsigned b = (e & 0x80000000u) ? (e & 0x7fffffffu) : ~e;
    return __uint_as_float(b);
}
#define ENC_SENT 0x34E76980u   // encodeF(-9999999.0f)

// LDS layout of raw fp32 weights (pre-loop fragment build only):
#define OW1 0
#define OB1 72
#define OW2 90
#define OB2 738
#define OW3 774
#define OB3 2070
#define OW4 2106
#define OB4 2142
#define NWTS 2143

// R11 history: R1=56us (LDS pipeline). R2 read-filter FAILED (cache
// ping-pong). R3/R4 ws-replication never engaged. R5 (8x XCD replicas +
// WORKGROUP-scope hint): ZERO delta, WRITE_SIZE unchanged -> scope hint
// didn't change the emitted instruction; same-line-chain theory falsified.
// R7 (LDS-free MFMA chain): all pipe counters moved, dur STILL 56us ->
// LDS theory falsified too. Across 4 structurally different kernels the
// only invariant is 1M scattered device-scope atomics = 17.9 Gop/s =
// ~1 op/17cyc/slice -> memory-side atomic ISSUE RATE is the floor
// (address-independent; explains R5's null).
// R8: force L2-local atomic execution: inline-asm global_atomic_umax with
// NO sc flags (sc0/sc1=00 = lowest scope -> executes at the XCD's L2,
// write-back) into XCD-private replicas (HW_REG_XCC_ID). All writers of
// replica j share XCD j's L2 = common coherence point; end-of-dispatch
// release writes L2 back for the decode merge. Falsifier: WRITE_SIZE
// 31MB -> <=10MB if atomics moved into L2.

__device__ unsigned g_rep[NREP * NCOLS];   // 2.25 MB static replica tables

__global__ __launch_bounds__(NTHR)
void mlp_scatter_mfma(const float* __restrict__ x, const int* __restrict__ tidx,
                      const float* __restrict__ W1, const float* __restrict__ b1,
                      const float* __restrict__ W2, const float* __restrict__ b2,
                      const float* __restrict__ W3, const float* __restrict__ b3,
                      const float* __restrict__ W4, const float* __restrict__ b4)
{
    __shared__ float sw[NWTS];          // raw fp32 weights (pre-loop use only)

    const int t    = threadIdx.x;
    const int lane = t & 63;
    const int quad = lane >> 4;
    const int n    = lane & 15;

    // ---- coalesced one-time stage of all weights into LDS ----
    for (int i = t; i < 72;   i += NTHR) sw[OW1 + i] = W1[i];
    for (int i = t; i < 18;   i += NTHR) sw[OB1 + i] = b1[i];
    for (int i = t; i < 648;  i += NTHR) sw[OW2 + i] = W2[i];
    for (int i = t; i < 36;   i += NTHR) sw[OB2 + i] = b2[i];
    for (int i = t; i < 1296; i += NTHR) sw[OW3 + i] = W3[i];
    for (int i = t; i < 36;   i += NTHR) sw[OB3 + i] = b3[i];
    for (int i = t; i < 36;   i += NTHR) sw[OW4 + i] = W4[i];
    if (t == 0) sw[OB4] = b4[0];
    __syncthreads();

    // ---- A-fragments of W (OUT x IN): tile tt (m = tt*16 + n), k-slice s ----
    auto af = [&](int off, int OUT, int IN, int tt, int s) {
        f16x4 r;
#pragma unroll
        for (int j = 0; j < 4; ++j) {
            const int m = tt * 16 + n;
            const int k = s * 16 + quad * 4 + j;
            const float w = (m < OUT && k < IN) ? sw[off + m * IN + k] : 0.0f;
            r[j] = (_Float16)w;
        }
        return r;
    };
    auto bv = [&](int off, int OUT, int tt) {
        f32x4 c;
#pragma unroll
        for (int r = 0; r < 4; ++r) {
            const int m = tt * 16 + quad * 4 + r;
            c[r] = (m < OUT) ? sw[off + m] : 0.0f;
        }
        return c;
    };

    const f16x4 A1_0  = af(OW1, 18,  4, 0, 0), A1_1  = af(OW1, 18,  4, 1, 0);
    const f16x4 A2_00 = af(OW2, 36, 18, 0, 0), A2_01 = af(OW2, 36, 18, 0, 1);
    const f16x4 A2_10 = af(OW2, 36, 18, 1, 0), A2_11 = af(OW2, 36, 18, 1, 1);
    const f16x4 A2_20 = af(OW2, 36, 18, 2, 0), A2_21 = af(OW2, 36, 18, 2, 1);
    const f16x4 A3_00 = af(OW3, 36, 36, 0, 0), A3_01 = af(OW3, 36, 36, 0, 1), A3_02 = af(OW3, 36, 36, 0, 2);
    const f16x4 A3_10 = af(OW3, 36, 36, 1, 0), A3_11 = af(OW3, 36, 36, 1, 1), A3_12 = af(OW3, 36, 36, 1, 2);
    const f16x4 A3_20 = af(OW3, 36, 36, 2, 0), A3_21 = af(OW3, 36, 36, 2, 1), A3_22 = af(OW3, 36, 36, 2, 2);

    const f32x4 C1_0 = bv(OB1, 18, 0), C1_1 = bv(OB1, 18, 1);
    const f32x4 C2_0 = bv(OB2, 36, 0), C2_1 = bv(OB2, 36, 1), C2_2 = bv(OB2, 36, 2);
    const f32x4 C3_0 = bv(OB3, 36, 0), C3_1 = bv(OB3, 36, 1), C3_2 = bv(OB3, 36, 2);
    const f32x4 V4_0 = bv(OW4, 36, 0), V4_1 = bv(OW4, 36, 1), V4_2 = bv(OW4, 36, 2);
    const float b4s  = sw[OB4];

    // ---- replica owned by this block's PHYSICAL XCD ----
    unsigned xcc;
    asm volatile("s_getreg_b32 %0, hwreg(HW_REG_XCC_ID)" : "=s"(xcc));
    unsigned* __restrict__ dst = g_rep + (size_t)(xcc & (NREP - 1)) * NCOLS;

    const int gw = (blockIdx.x * blockDim.x + t) >> 6;
    const int nw = (gridDim.x * blockDim.x) >> 6;

    // ---- prefetch-rotate state for pair p ----
    float cxa0, cxa1, cxa2, cxa3, cxb0, cxb1, cxb2, cxb3;
    int cca = 0, ccb = 0;
    if (gw < NPAIRS) {
        const int kb = gw * 32;
        cxa0 = x[0 * KN + kb + n];      cxb0 = x[0 * KN + kb + 16 + n];
        cxa1 = x[1 * KN + kb + n];      cxb1 = x[1 * KN + kb + 16 + n];
        cxa2 = x[2 * KN + kb + n];      cxb2 = x[2 * KN + kb + 16 + n];
        cxa3 = x[3 * KN + kb + n];      cxb3 = x[3 * KN + kb + 16 + n];
        cca  = tidx[2 * (kb + n) + 1];  ccb  = tidx[2 * (kb + 16 + n) + 1];
    }

    auto rl = [](f32x4 v) {            // relu + f32->f16, layout-preserving
        f16x4 h;
#pragma unroll
        for (int r = 0; r < 4; ++r) h[r] = (_Float16)fmaxf(v[r], 0.0f);
        return h;
    };

    for (int p = gw; p < NPAIRS; ) {
        const int pn = p + nw;
        const float xa0 = cxa0, xa1 = cxa1, xa2 = cxa2, xa3 = cxa3;
        const float xb0 = cxb0, xb1 = cxb1, xb2 = cxb2, xb3 = cxb3;
        const int cola = cca, colb = ccb;
        if (pn < NPAIRS) {
            const int kb = pn * 32;
            cxa0 = x[0 * KN + kb + n];      cxb0 = x[0 * KN + kb + 16 + n];
            cxa1 = x[1 * KN + kb + n];      cxb1 = x[1 * KN + kb + 16 + n];
            cxa2 = x[2 * KN + kb + n];      cxb2 = x[2 * KN + kb + 16 + n];
            cxa3 = x[3 * KN + kb + n];      cxb3 = x[3 * KN + kb + 16 + n];
            cca  = tidx[2 * (kb + n) + 1];  ccb  = tidx[2 * (kb + 16 + n) + 1];
        }

        // ---- B0 = x^T fragment (real k<4 -> quad 0) ----
        f16x4 B0a = {}, B0b = {};
        if (quad == 0) {
            B0a[0] = (_Float16)xa0; B0a[1] = (_Float16)xa1;
            B0a[2] = (_Float16)xa2; B0a[3] = (_Float16)xa3;
            B0b[0] = (_Float16)xb0; B0b[1] = (_Float16)xb1;
            B0b[2] = (_Float16)xb2; B0b[3] = (_Float16)xb3;
        }

        // ---- L1 ----
        f32x4 d1a0 = MFMA16(A1_0, B0a, C1_0);
        f32x4 d1b0 = MFMA16(A1_0, B0b, C1_0);
        f32x4 d1a1 = MFMA16(A1_1, B0a, C1_1);
        f32x4 d1b1 = MFMA16(A1_1, B0b, C1_1);
        const f16x4 B1a0 = rl(d1a0), B1a1 = rl(d1a1);
        const f16x4 B1b0 = rl(d1b0), B1b1 = rl(d1b1);

        // ---- L2 ----
        f32x4 d2a0 = MFMA16(A2_00, B1a0, C2_0);  d2a0 = MFMA16(A2_01, B1a1, d2a0);
        f32x4 d2b0 = MFMA16(A2_00, B1b0, C2_0);  d2b0 = MFMA16(A2_01, B1b1, d2b0);
        f32x4 d2a1 = MFMA16(A2_10, B1a0, C2_1);  d2a1 = MFMA16(A2_11, B1a1, d2a1);
        f32x4 d2b1 = MFMA16(A2_10, B1b0, C2_1);  d2b1 = MFMA16(A2_11, B1b1, d2b1);
        f32x4 d2a2 = MFMA16(A2_20, B1a0, C2_2);  d2a2 = MFMA16(A2_21, B1a1, d2a2);
        f32x4 d2b2 = MFMA16(A2_20, B1b0, C2_2);  d2b2 = MFMA16(A2_21, B1b1, d2b2);
        const f16x4 B2a0 = rl(d2a0), B2a1 = rl(d2a1), B2a2 = rl(d2a2);
        const f16x4 B2b0 = rl(d2b0), B2b1 = rl(d2b1), B2b2 = rl(d2b2);

        // ---- L3 ----
        f32x4 d3a0 = MFMA16(A3_00, B2a0, C3_0);
        d3a0 = MFMA16(A3_01, B2a1, d3a0);  d3a0 = MFMA16(A3_02, B2a2, d3a0);
        f32x4 d3b0 = MFMA16(A3_00, B2b0, C3_0);
        d3b0 = MFMA16(A3_01, B2b1, d3b0);  d3b0 = MFMA16(A3_02, B2b2, d3b0);
        f32x4 d3a1 = MFMA16(A3_10, B2a0, C3_1);
        d3a1 = MFMA16(A3_11, B2a1, d3a1);  d3a1 = MFMA16(A3_12, B2a2, d3a1);
        f32x4 d3b1 = MFMA16(A3_10, B2b0, C3_1);
        d3b1 = MFMA16(A3_11, B2b1, d3b1);  d3b1 = MFMA16(A3_12, B2b2, d3b1);
        f32x4 d3a2 = MFMA16(A3_20, B2a0, C3_2);
        d3a2 = MFMA16(A3_21, B2a1, d3a2);  d3a2 = MFMA16(A3_22, B2a2, d3a2);
        f32x4 d3b2 = MFMA16(A3_20, B2b0, C3_2);
        d3b2 = MFMA16(A3_21, B2b1, d3b2);  d3b2 = MFMA16(A3_22, B2b2, d3b2);

        // ---- L4: per-lane partial over its 12 feats, reduce across quads ----
        float pa = 0.0f, pb = 0.0f;
#pragma unroll
        for (int r = 0; r < 4; ++r) {
            pa = fmaf(V4_0[r], fmaxf(d3a0[r], 0.0f), pa);
            pa = fmaf(V4_1[r], fmaxf(d3a1[r], 0.0f), pa);
            pa = fmaf(V4_2[r], fmaxf(d3a2[r], 0.0f), pa);
            pb = fmaf(V4_0[r], fmaxf(d3b0[r], 0.0f), pb);
            pb = fmaf(V4_1[r], fmaxf(d3b1[r], 0.0f), pb);
            pb = fmaf(V4_2[r], fmaxf(d3b2[r], 0.0f), pb);
        }
        pa += __shfl_xor(pa, 16);  pa += __shfl_xor(pa, 32);
        pb += __shfl_xor(pb, 16);  pb += __shfl_xor(pb, 32);

        // ---- flagless (sc0/sc1=00) atomic -> executes at THIS XCD's L2,
        //      write-back; replica is XCD-private so L2 is the valid
        //      coherence point for all its writers ----
        if (quad == 0) {
            const unsigned ea = encodeF(pa + b4s) - ENC_SENT;
            unsigned* ap = &dst[cola];
            asm volatile("global_atomic_umax %0, %1, off"
                         :: "v"(ap), "v"(ea) : "memory");
        } else if (quad == 1) {
            const unsigned eb = encodeF(pb + b4s) - ENC_SENT;
            unsigned* bp = &dst[colb];
            asm volatile("global_atomic_umax %0, %1, off"
                         :: "v"(bp), "v"(eb) : "memory");
        }

        p = pn;
    }
}

__global__ __launch_bounds__(256) void init_kernel() {
    int gid = blockIdx.x * blockDim.x + threadIdx.x;
    if (gid < NREP * NCOLS) g_rep[gid] = 0u;   // == encode(SENTINEL) - bias
}

__global__ __launch_bounds__(256) void decode_kernel(float* __restrict__ out,
                                                     int out_size) {
    int gid = blockIdx.x * blockDim.x + threadIdx.x;
    if (gid < out_size) {
        float r = 1.0f;
        if (gid < NCOLS) {
            unsigned m = g_rep[gid];
#pragma unroll
            for (int i = 1; i < NREP; ++i) {
                unsigned v = g_rep[i * NCOLS + gid];
                m = (v > m) ? v : m;
            }
            r = decodeF(m + ENC_SENT);
        }
        out[gid] = r;
    }
}

extern "C" void kernel_launch(void* const* d_in, const int* in_sizes, int n_in,
                              void* d_out, int out_size, void* d_ws, size_t ws_size,
                              hipStream_t stream) {
    const float* x    = (const float*)d_in[0];   // (1,4,1,K)
    const int*   tidx = (const int*)d_in[1];     // (K,2)
    const float* W1 = (const float*)d_in[2];
    const float* b1 = (const float*)d_in[3];
    const float* W2 = (const float*)d_in[4];
    const float* b2 = (const float*)d_in[5];
    const float* W3 = (const float*)d_in[6];
    const float* b3 = (const float*)d_in[7];
    const float* W4 = (const float*)d_in[8];
    const float* b4 = (const float*)d_in[9];

    init_kernel<<<(NREP * NCOLS + 255) / 256, 256, 0, stream>>>();

    mlp_scatter_mfma<<<NBLK, NTHR, 0, stream>>>(
        x, tidx, W1, b1, W2, b2, W3, b3, W4, b4);

    decode_kernel<<<(out_size + 255) / 256, 256, 0, stream>>>(
        (float*)d_out, out_size);
}

// Round 9
// 130.041 us; speedup vs baseline: 1.0512x; 1.0512x over previous
//
#include <hip/hip_runtime.h>

#define KN 1000000
#define NCOLS 70400
#define NTHR 256
#define CHUNK 2048                 // elements per phase-1 block
#define KBLK 489                   // ceil(KN / CHUNK)
#define NBUK 275                   // col >> 8  (70400 = 275 * 256 exactly)
#define CAP 40                     // slots per (block,bucket); lambda = 7.45

typedef _Float16 f16x4 __attribute__((ext_vector_type(4)));
typedef float    f32x4 __attribute__((ext_vector_type(4)));

// 16x16x16 f16 MFMA: A[m][k] m=lane&15, k=quad*4+j; B[k][n] n=lane&15,
// k=quad*4+j; D[m][n] n=lane&15, m=quad*4+r.  A, B, D share per-lane
// structure -> relu(D) of layer L is directly the B-operand of layer L+1.
#define MFMA16(a, b, c) __builtin_amdgcn_mfma_f32_16x16x16f16((a), (b), (c), 0, 0, 0)

__device__ __forceinline__ unsigned encodeF(float f) {
    unsigned b = __float_as_uint(f);
    return (b & 0x80000000u) ? ~b : (b | 0x80000000u);
}
__device__ __forceinline__ float decodeF(unsigned e) {
    unsigned b = (e & 0x80000000u) ? (e & 0x7fffffffu) : ~e;
    return __uint_as_float(b);
}
#define ENC_SENT 0x34E76980u   // encodeF(-9999999.0f)

// LDS layout of raw fp32 weights (pre-loop fragment build only):
#define OW1 0
#define OB1 72
#define OW2 90
#define OB2 738
#define OW3 774
#define OB3 2070
#define OW4 2106
#define OB4 2142
#define NWTS 2143

// R11 history: R1-R8 all pinned at 55-57us across 6 structurally different
// kernels (LDS pipeline / read filter / d_ws replicas / XCD replicas+scope /
// LDS-free MFMA chain / flagless asm atomics). WRITE_SIZE is always
// ~31-44B x 1M atomics regardless of destination footprint or scope ->
// scattered global atomics execute memory-side at a fixed ~18 Gop/s op rate
// (~14 cyc/slice/op); same-line chains, XCD locality, sc flags all
// irrelevant. R2 showed cached reads of atomic-hot lines are poison.
// R9: ELIMINATE global atomics. Phase 1 = R7's MFMA chain + LDS-binned
// (col,enc) pairs -> per-(block,bucket) regions via plain 8B stores
// (bucket = col>>8, 275 buckets x 256 cols). Phase 2 = one block per
// bucket: gather regions, LDS atomicMax, plain coalesced final stores.
// Zero global atomics anywhere; init/decode kernels gone (2 launches).

__device__ uint2    g_bin[(size_t)KBLK * NBUK * CAP];   // 43 MB static
__device__ unsigned g_cnt[KBLK * NBUK];

__global__ __launch_bounds__(NTHR)
void mlp_bin(const float* __restrict__ x, const int* __restrict__ tidx,
             const float* __restrict__ W1, const float* __restrict__ b1,
             const float* __restrict__ W2, const float* __restrict__ b2,
             const float* __restrict__ W3, const float* __restrict__ b3,
             const float* __restrict__ W4, const float* __restrict__ b4)
{
    __shared__ float    sw[NWTS];      // raw fp32 weights (pre-loop use only)
    __shared__ unsigned bcnt[NBUK];    // per-block bucket counters

    const int t    = threadIdx.x;
    const int lane = t & 63;
    const int quad = lane >> 4;
    const int n    = lane & 15;

    // ---- coalesced one-time stage of all weights into LDS ----
    for (int i = t; i < 72;   i += NTHR) sw[OW1 + i] = W1[i];
    for (int i = t; i < 18;   i += NTHR) sw[OB1 + i] = b1[i];
    for (int i = t; i < 648;  i += NTHR) sw[OW2 + i] = W2[i];
    for (int i = t; i < 36;   i += NTHR) sw[OB2 + i] = b2[i];
    for (int i = t; i < 1296; i += NTHR) sw[OW3 + i] = W3[i];
    for (int i = t; i < 36;   i += NTHR) sw[OB3 + i] = b3[i];
    for (int i = t; i < 36;   i += NTHR) sw[OW4 + i] = W4[i];
    if (t == 0) sw[OB4] = b4[0];
    for (int i = t; i < NBUK; i += NTHR) bcnt[i] = 0u;
    __syncthreads();

    // ---- A-fragments of W (OUT x IN): tile tt (m = tt*16 + n), k-slice s ----
    auto af = [&](int off, int OUT, int IN, int tt, int s) {
        f16x4 r;
#pragma unroll
        for (int j = 0; j < 4; ++j) {
            const int m = tt * 16 + n;
            const int k = s * 16 + quad * 4 + j;
            const float w = (m < OUT && k < IN) ? sw[off + m * IN + k] : 0.0f;
            r[j] = (_Float16)w;
        }
        return r;
    };
    auto bv = [&](int off, int OUT, int tt) {
        f32x4 c;
#pragma unroll
        for (int r = 0; r < 4; ++r) {
            const int m = tt * 16 + quad * 4 + r;
            c[r] = (m < OUT) ? sw[off + m] : 0.0f;
        }
        return c;
    };

    const f16x4 A1_0  = af(OW1, 18,  4, 0, 0), A1_1  = af(OW1, 18,  4, 1, 0);
    const f16x4 A2_00 = af(OW2, 36, 18, 0, 0), A2_01 = af(OW2, 36, 18, 0, 1);
    const f16x4 A2_10 = af(OW2, 36, 18, 1, 0), A2_11 = af(OW2, 36, 18, 1, 1);
    const f16x4 A2_20 = af(OW2, 36, 18, 2, 0), A2_21 = af(OW2, 36, 18, 2, 1);
    const f16x4 A3_00 = af(OW3, 36, 36, 0, 0), A3_01 = af(OW3, 36, 36, 0, 1), A3_02 = af(OW3, 36, 36, 0, 2);
    const f16x4 A3_10 = af(OW3, 36, 36, 1, 0), A3_11 = af(OW3, 36, 36, 1, 1), A3_12 = af(OW3, 36, 36, 1, 2);
    const f16x4 A3_20 = af(OW3, 36, 36, 2, 0), A3_21 = af(OW3, 36, 36, 2, 1), A3_22 = af(OW3, 36, 36, 2, 2);

    const f32x4 C1_0 = bv(OB1, 18, 0), C1_1 = bv(OB1, 18, 1);
    const f32x4 C2_0 = bv(OB2, 36, 0), C2_1 = bv(OB2, 36, 1), C2_2 = bv(OB2, 36, 2);
    const f32x4 C3_0 = bv(OB3, 36, 0), C3_1 = bv(OB3, 36, 1), C3_2 = bv(OB3, 36, 2);
    const f32x4 V4_0 = bv(OW4, 36, 0), V4_1 = bv(OW4, 36, 1), V4_2 = bv(OW4, 36, 2);
    const float b4s  = sw[OB4];

    const int base = blockIdx.x * CHUNK;
    const int lim  = (base + CHUNK < KN) ? base + CHUNK : KN;

    auto rl = [](f32x4 v) {            // relu + f32->f16, layout-preserving
        f16x4 h;
#pragma unroll
        for (int r = 0; r < 4; ++r) h[r] = (_Float16)fmaxf(v[r], 0.0f);
        return h;
    };

    // ---- prefetch-rotate over this block's chunk (wave wv owns kb steps
    //      of 128 starting at base + wv*32) ----
    int kb = base + (t >> 6) * 32;
    float cxa0, cxa1, cxa2, cxa3, cxb0, cxb1, cxb2, cxb3;
    int cca = 0, ccb = 0;
    if (kb < lim) {
        cxa0 = x[0 * KN + kb + n];      cxb0 = x[0 * KN + kb + 16 + n];
        cxa1 = x[1 * KN + kb + n];      cxb1 = x[1 * KN + kb + 16 + n];
        cxa2 = x[2 * KN + kb + n];      cxb2 = x[2 * KN + kb + 16 + n];
        cxa3 = x[3 * KN + kb + n];      cxb3 = x[3 * KN + kb + 16 + n];
        cca  = tidx[2 * (kb + n) + 1];  ccb  = tidx[2 * (kb + 16 + n) + 1];
    }

    for (; kb < lim; kb += 128) {
        const int kbn = kb + 128;
        const float xa0 = cxa0, xa1 = cxa1, xa2 = cxa2, xa3 = cxa3;
        const float xb0 = cxb0, xb1 = cxb1, xb2 = cxb2, xb3 = cxb3;
        const int cola = cca, colb = ccb;
        if (kbn < lim) {
            cxa0 = x[0 * KN + kbn + n];      cxb0 = x[0 * KN + kbn + 16 + n];
            cxa1 = x[1 * KN + kbn + n];      cxb1 = x[1 * KN + kbn + 16 + n];
            cxa2 = x[2 * KN + kbn + n];      cxb2 = x[2 * KN + kbn + 16 + n];
            cxa3 = x[3 * KN + kbn + n];      cxb3 = x[3 * KN + kbn + 16 + n];
            cca  = tidx[2 * (kbn + n) + 1];  ccb  = tidx[2 * (kbn + 16 + n) + 1];
        }

        // ---- B0 = x^T fragment (real k<4 -> quad 0) ----
        f16x4 B0a = {}, B0b = {};
        if (quad == 0) {
            B0a[0] = (_Float16)xa0; B0a[1] = (_Float16)xa1;
            B0a[2] = (_Float16)xa2; B0a[3] = (_Float16)xa3;
            B0b[0] = (_Float16)xb0; B0b[1] = (_Float16)xb1;
            B0b[2] = (_Float16)xb2; B0b[3] = (_Float16)xb3;
        }

        // ---- L1 ----
        f32x4 d1a0 = MFMA16(A1_0, B0a, C1_0);
        f32x4 d1b0 = MFMA16(A1_0, B0b, C1_0);
        f32x4 d1a1 = MFMA16(A1_1, B0a, C1_1);
        f32x4 d1b1 = MFMA16(A1_1, B0b, C1_1);
        const f16x4 B1a0 = rl(d1a0), B1a1 = rl(d1a1);
        const f16x4 B1b0 = rl(d1b0), B1b1 = rl(d1b1);

        // ---- L2 ----
        f32x4 d2a0 = MFMA16(A2_00, B1a0, C2_0);  d2a0 = MFMA16(A2_01, B1a1, d2a0);
        f32x4 d2b0 = MFMA16(A2_00, B1b0, C2_0);  d2b0 = MFMA16(A2_01, B1b1, d2b0);
        f32x4 d2a1 = MFMA16(A2_10, B1a0, C2_1);  d2a1 = MFMA16(A2_11, B1a1, d2a1);
        f32x4 d2b1 = MFMA16(A2_10, B1b0, C2_1);  d2b1 = MFMA16(A2_11, B1b1, d2b1);
        f32x4 d2a2 = MFMA16(A2_20, B1a0, C2_2);  d2a2 = MFMA16(A2_21, B1a1, d2a2);
        f32x4 d2b2 = MFMA16(A2_20, B1b0, C2_2);  d2b2 = MFMA16(A2_21, B1b1, d2b2);
        const f16x4 B2a0 = rl(d2a0), B2a1 = rl(d2a1), B2a2 = rl(d2a2);
        const f16x4 B2b0 = rl(d2b0), B2b1 = rl(d2b1), B2b2 = rl(d2b2);

        // ---- L3 ----
        f32x4 d3a0 = MFMA16(A3_00, B2a0, C3_0);
        d3a0 = MFMA16(A3_01, B2a1, d3a0);  d3a0 = MFMA16(A3_02, B2a2, d3a0);
        f32x4 d3b0 = MFMA16(A3_00, B2b0, C3_0);
        d3b0 = MFMA16(A3_01, B2b1, d3b0);  d3b0 = MFMA16(A3_02, B2b2, d3b0);
        f32x4 d3a1 = MFMA16(A3_10, B2a0, C3_1);
        d3a1 = MFMA16(A3_11, B2a1, d3a1);  d3a1 = MFMA16(A3_12, B2a2, d3a1);
        f32x4 d3b1 = MFMA16(A3_10, B2b0, C3_1);
        d3b1 = MFMA16(A3_11, B2b1, d3b1);  d3b1 = MFMA16(A3_12, B2b2, d3b1);
        f32x4 d3a2 = MFMA16(A3_20, B2a0, C3_2);
        d3a2 = MFMA16(A3_21, B2a1, d3a2);  d3a2 = MFMA16(A3_22, B2a2, d3a2);
        f32x4 d3b2 = MFMA16(A3_20, B2b0, C3_2);
        d3b2 = MFMA16(A3_21, B2b1, d3b2);  d3b2 = MFMA16(A3_22, B2b2, d3b2);

        // ---- L4: per-lane partial over its 12 feats, reduce across quads ----
        float pa = 0.0f, pb = 0.0f;
#pragma unroll
        for (int r = 0; r < 4; ++r) {
            pa = fmaf(V4_0[r], fmaxf(d3a0[r], 0.0f), pa);
            pa = fmaf(V4_1[r], fmaxf(d3a1[r], 0.0f), pa);
            pa = fmaf(V4_2[r], fmaxf(d3a2[r], 0.0f), pa);
            pb = fmaf(V4_0[r], fmaxf(d3b0[r], 0.0f), pb);
            pb = fmaf(V4_1[r], fmaxf(d3b1[r], 0.0f), pb);
            pb = fmaf(V4_2[r], fmaxf(d3b2[r], 0.0f), pb);
        }
        pa += __shfl_xor(pa, 16);  pa += __shfl_xor(pa, 32);
        pb += __shfl_xor(pb, 16);  pb += __shfl_xor(pb, 32);

        // ---- LDS-binned emit: quad0 emits element a, quad1 element b ----
        if (quad < 2) {
            const int   col = (quad == 0) ? cola : colb;
            const float pv  = (quad == 0) ? pa   : pb;
            const unsigned enc = encodeF(pv + b4s) - ENC_SENT;
            const int bk = col >> 8;
            const unsigned slot = atomicAdd(&bcnt[bk], 1u);   // LDS atomic
            if (slot < CAP) {
                uint2 e;
                e.x = (unsigned)(col & 255);
                e.y = enc;
                g_bin[((size_t)blockIdx.x * NBUK + bk) * CAP + slot] = e;
            }
        }
    }

    __syncthreads();
    for (int i = t; i < NBUK; i += NTHR) {
        unsigned c = bcnt[i];
        g_cnt[blockIdx.x * NBUK + i] = (c > CAP) ? CAP : c;
    }
}

__global__ __launch_bounds__(NTHR)
void bucket_reduce(float* __restrict__ out, int out_size)
{
    __shared__ unsigned tab[256];
    const int b = blockIdx.x;          // bucket id, 0..NBUK-1
    const int t = threadIdx.x;

    tab[t] = 0u;                       // == encode(SENTINEL) - bias
    __syncthreads();

    for (int rb = t; rb < KBLK; rb += NTHR) {
        unsigned c = g_cnt[rb * NBUK + b];
        if (c > CAP) c = CAP;
        const uint2* reg = &g_bin[((size_t)rb * NBUK + b) * CAP];
        for (unsigned s = 0; s < c; ++s) {
            const uint2 e = reg[s];
            atomicMax(&tab[e.x], e.y); // LDS atomic
        }
    }
    __syncthreads();

    const int gid = b * 256 + t;
    if (gid < out_size) out[gid] = decodeF(tab[t] + ENC_SENT);
    if (b == 0) {
        for (int i = NCOLS + t; i < out_size; i += NTHR) out[i] = 1.0f;
    }
}

extern "C" void kernel_launch(void* const* d_in, const int* in_sizes, int n_in,
                              void* d_out, int out_size, void* d_ws, size_t ws_size,
                              hipStream_t stream) {
    const float* x    = (const float*)d_in[0];   // (1,4,1,K)
    const int*   tidx = (const int*)d_in[1];     // (K,2)
    const float* W1 = (const float*)d_in[2];
    const float* b1 = (const float*)d_in[3];
    const float* W2 = (const float*)d_in[4];
    const float* b2 = (const float*)d_in[5];
    const float* W3 = (const float*)d_in[6];
    const float* b3 = (const float*)d_in[7];
    const float* W4 = (const float*)d_in[8];
    const float* b4 = (const float*)d_in[9];

    mlp_bin<<<KBLK, NTHR, 0, stream>>>(x, tidx, W1, b1, W2, b2, W3, b3, W4, b4);

    bucket_reduce<<<NBUK, NTHR, 0, stream>>>((float*)d_out, out_size);
}